// Round 8
// baseline (2512.652 us; speedup 1.0000x reference)
//
#include <hip/hip_runtime.h>
#include <hip/hip_bf16.h>
#include <cstddef>

// Problem dims (fixed)
#define BB 256
#define CC 512
#define SS 128      // FH*FW = 8*16
#define HH 512
#define VV 64
#define LL 24       // sequence length; steps = 23

typedef unsigned short ush;
typedef __attribute__((ext_vector_type(8))) short short8;
typedef __attribute__((ext_vector_type(4))) float f32x4;

__device__ __forceinline__ float wave_sum(float v) {
#pragma unroll
    for (int off = 32; off > 0; off >>= 1) v += __shfl_xor(v, off);
    return v;
}
__device__ __forceinline__ float wave_max(float v) {
#pragma unroll
    for (int off = 32; off > 0; off >>= 1) v = fmaxf(v, __shfl_xor(v, off));
    return v;
}
__device__ __forceinline__ float sigm(float x) { return 1.0f / (1.0f + expf(-x)); }
__device__ __forceinline__ ush f2bf(float f) {
    unsigned u = __float_as_uint(f);
    u += 0x7FFFu + ((u >> 16) & 1u);
    return (ush)(u >> 16);
}
__device__ __forceinline__ float bf2f(ush b) {
    return __uint_as_float(((unsigned)b) << 16);
}
__device__ __forceinline__ unsigned pack2(float a, float b) {
    return (unsigned)f2bf(a) | ((unsigned)f2bf(b) << 16);
}

// ---------------------------------------------------------------------------
// Fused weight conversion: 8 segments, one f4 per thread. Total 1253376 f4s.
struct ConvAllArgs {
    const float* src[8];
    ush* dst[8];
};
__global__ __launch_bounds__(256) void conv_all(ConvAllArgs a) {
    int i = blockIdx.x * 256 + threadIdx.x;
    int seg, base;
    if (i < 65536)        { seg = 0; base = 0; }
    else if (i < 131072)  { seg = 1; base = 65536; }
    else if (i < 262144)  { seg = 2; base = 131072; }
    else if (i < 270336)  { seg = 3; base = 262144; }
    else if (i < 663552)  { seg = 4; base = 270336; }
    else if (i < 860160)  { seg = 5; base = 663552; }
    else if (i < 1056768) { seg = 6; base = 860160; }
    else                  { seg = 7; base = 1056768; }
    int j = i - base;
    float4 v = ((const float4*)a.src[seg])[j];
    uint2 o;
    o.x = pack2(v.x, v.y);
    o.y = pack2(v.z, v.w);
    ((uint2*)a.dst[seg])[j] = o;
}

// fp32 -> bf16 convert (enc), 4 elems/thread
__global__ __launch_bounds__(256) void conv_kernel(const float* __restrict__ src,
                                                   ush* __restrict__ dst, int n4) {
    int i = blockIdx.x * 256 + threadIdx.x;
    if (i < n4) {
        float4 v = ((const float4*)src)[i];
        uint2 o;
        o.x = pack2(v.x, v.y);
        o.y = pack2(v.z, v.w);
        ((uint2*)dst)[i] = o;
    }
}

// gather embeddings -> bf16
__global__ __launch_bounds__(128) void gather_kernel(const float* __restrict__ embed_w,
                                                     const int* __restrict__ seq,
                                                     ush* __restrict__ xall) {
    int item = blockIdx.x;           // t*256 + m
    int t = item >> 8, m = item & 255;
    int row = seq[m * LL + t];
    float4 v = ((const float4*)(embed_w + (size_t)row * HH))[threadIdx.x];
    uint2 o;
    o.x = pack2(v.x, v.y);
    o.y = pack2(v.z, v.w);
    ((uint2*)(xall + (size_t)item * HH))[threadIdx.x] = o;
}

// init: h states fp32+bf16, zero acc
__global__ __launch_bounds__(256) void init_kernel(const float* __restrict__ is,
                                                   float* __restrict__ h0,
                                                   float* __restrict__ h1,
                                                   ush* __restrict__ h0b,
                                                   ush* __restrict__ h1b,
                                                   float* __restrict__ acc) {
    int idx = blockIdx.x * 256 + threadIdx.x;
    if (idx < BB * HH) {
        float a = is[idx & 511];
        float b = is[512 + (idx & 511)];
        h0[idx] = a; h1[idx] = b;
        h0b[idx] = f2bf(a); h1b[idx] = f2bf(b);
    }
    if (idx < 2) acc[idx] = 0.0f;
}

// ---------------------------------------------------------------------------
// mfma_tile64 (proven): A row=l16 k=quad*8+j; B row=l16; D col=l16, row=quad*4+r
__device__ __forceinline__ void mfma_tile64(const ush* xp, const ush* wp, size_t wst,
                                            f32x4 acc[4]) {
    short8 a_c = *(const short8*)xp;
    short8 b0 = *(const short8*)(wp);
    short8 b1 = *(const short8*)(wp + 16 * wst);
    short8 b2 = *(const short8*)(wp + 32 * wst);
    short8 b3 = *(const short8*)(wp + 48 * wst);
#pragma unroll
    for (int ks = 0; ks < 16; ks++) {
        short8 a_n, c0, c1, c2, c3;
        if (ks < 15) {
            int k = (ks + 1) * 32;
            a_n = *(const short8*)(xp + k);
            c0 = *(const short8*)(wp + k);
            c1 = *(const short8*)(wp + 16 * wst + k);
            c2 = *(const short8*)(wp + 32 * wst + k);
            c3 = *(const short8*)(wp + 48 * wst + k);
        }
        acc[0] = __builtin_amdgcn_mfma_f32_16x16x32_bf16(a_c, b0, acc[0], 0, 0, 0);
        acc[1] = __builtin_amdgcn_mfma_f32_16x16x32_bf16(a_c, b1, acc[1], 0, 0, 0);
        acc[2] = __builtin_amdgcn_mfma_f32_16x16x32_bf16(a_c, b2, acc[2], 0, 0, 0);
        acc[3] = __builtin_amdgcn_mfma_f32_16x16x32_bf16(a_c, b3, acc[3], 0, 0, 0);
        if (ks < 15) { a_c = a_n; b0 = c0; b1 = c1; b2 = c2; b3 = c3; }
    }
}

// ---------------------------------------------------------------------------
// Ws MFMA (proven R3): grid (128, 8), block 256. Out bf16.
__global__ __launch_bounds__(256) void ws_mfma(const float* __restrict__ enc,
                                               const ush* __restrict__ Wb,
                                               const float* __restrict__ bias,
                                               ush* __restrict__ Ws_bf) {
    int tid = threadIdx.x;
    int wave = tid >> 6, lane = tid & 63;
    int quad = lane >> 4, l16 = lane & 15;
    int m0 = blockIdx.x * 256 + wave * 64;
    int n0 = blockIdx.y * 64;
    int b = m0 >> 7;
    int s_base = m0 & 127;
    const float* eb = enc + (size_t)b * CC * SS;
    const ush* wp = Wb + (size_t)(n0 + l16) * 512 + quad * 8;
    f32x4 acc[4][4];
#pragma unroll
    for (int f = 0; f < 4; f++)
#pragma unroll
        for (int s = 0; s < 4; s++) acc[f][s] = (f32x4){0.f, 0.f, 0.f, 0.f};
    for (int k0 = 0; k0 < 512; k0 += 32) {
        short8 af[4], bfr[4];
#pragma unroll
        for (int f = 0; f < 4; f++) {
            int s = s_base + f * 16 + l16;
#pragma unroll
            for (int j = 0; j < 8; j++) {
                float v = eb[(size_t)(k0 + quad * 8 + j) * SS + s];
                af[f][j] = (short)f2bf(v);
            }
        }
#pragma unroll
        for (int s = 0; s < 4; s++)
            bfr[s] = *(const short8*)(wp + (size_t)s * 16 * 512 + k0);
#pragma unroll
        for (int f = 0; f < 4; f++)
#pragma unroll
            for (int s = 0; s < 4; s++)
                acc[f][s] = __builtin_amdgcn_mfma_f32_16x16x32_bf16(af[f], bfr[s], acc[f][s], 0, 0, 0);
    }
#pragma unroll
    for (int f = 0; f < 4; f++)
#pragma unroll
        for (int s = 0; s < 4; s++)
#pragma unroll
            for (int r = 0; r < 4; r++) {
                int m = m0 + f * 16 + quad * 4 + r;
                int n = n0 + s * 16 + l16;
                Ws_bf[(size_t)m * HH + n] = f2bf(acc[f][s][r] + bias[n]);
            }
}

// ---------------------------------------------------------------------------
// GRU, gate-per-wave: grid 512 (16 rowgroups x 32 colgroups, XCD-swizzled),
// block 192 = 3 waves (wave0=r, wave1=z, wave2=n). Each wave: one full gate
// chain over all K phases; gates exchanged via LDS; wave0 does the epilogue.
template <bool HASX, int KI>
__global__ __launch_bounds__(192) void gru3(const ush* __restrict__ xa,
                                            const ush* __restrict__ xt,
                                            const ush* __restrict__ hA,
                                            const ush* __restrict__ wi,
                                            const ush* __restrict__ wh,
                                            const float* __restrict__ bih,
                                            const float* __restrict__ bhh,
                                            const float* __restrict__ h_prev,
                                            float* __restrict__ h_out,
                                            ush* __restrict__ h_out_bf) {
    __shared__ float buf[4][256];
    int tid = threadIdx.x;
    int wave = tid / 64, lane = tid & 63;
    int quad = lane >> 4, l16 = lane & 15;
    int q = blockIdx.x & 7;
    int idx = blockIdx.x >> 3;           // 0..63
    int cg = q * 4 + (idx & 3);          // 0..31
    int rg = idx >> 2;                   // 0..15
    int m0 = rg * 16;
    int nrow = cg * 16 + l16;            // 0..511
    const ush* wip = wi + ((size_t)(wave * 512) + nrow) * KI + quad * 8;
    const ush* whp = wh + ((size_t)(wave * 512) + nrow) * 512 + quad * 8;
    const ush* ap = xa + (size_t)(m0 + l16) * 512 + quad * 8;
    f32x4 acc1 = (f32x4){0.f, 0.f, 0.f, 0.f};
    f32x4 acc2 = acc1;
#pragma unroll
    for (int ks = 0; ks < 16; ks++)
        acc1 = __builtin_amdgcn_mfma_f32_16x16x32_bf16(
            *(const short8*)(ap + ks * 32), *(const short8*)(wip + ks * 32), acc1, 0, 0, 0);
    if (HASX) {
        const ush* xp = xt + (size_t)(m0 + l16) * 512 + quad * 8;
#pragma unroll
        for (int ks = 0; ks < 16; ks++)
            acc1 = __builtin_amdgcn_mfma_f32_16x16x32_bf16(
                *(const short8*)(xp + ks * 32), *(const short8*)(wip + 512 + ks * 32), acc1, 0, 0, 0);
    }
    {
        const ush* hp = hA + (size_t)(m0 + l16) * 512 + quad * 8;
#pragma unroll
        for (int ks = 0; ks < 16; ks++)
            acc2 = __builtin_amdgcn_mfma_f32_16x16x32_bf16(
                *(const short8*)(hp + ks * 32), *(const short8*)(whp + ks * 32), acc2, 0, 0, 0);
    }
    if (wave < 2) {
#pragma unroll
        for (int r = 0; r < 4; r++)
            buf[wave][(quad * 4 + r) * 16 + l16] = acc1[r] + acc2[r];
    } else {
#pragma unroll
        for (int r = 0; r < 4; r++) {
            buf[2][(quad * 4 + r) * 16 + l16] = acc1[r];
            buf[3][(quad * 4 + r) * 16 + l16] = acc2[r];
        }
    }
    __syncthreads();
    if (wave == 0) {
        int n = nrow;
        float br = bih[n] + bhh[n];
        float bz = bih[512 + n] + bhh[512 + n];
        float bin = bih[1024 + n];
        float bhn = bhh[1024 + n];
#pragma unroll
        for (int rr = 0; rr < 4; rr++) {
            int e = (quad * 4 + rr) * 16 + l16;
            int m = m0 + quad * 4 + rr;
            float r = sigm(buf[0][e] + br);
            float z = sigm(buf[1][e] + bz);
            float na = tanhf(buf[2][e] + bin + r * (buf[3][e] + bhn));
            float hp = h_prev[(size_t)m * 512 + n];
            float ho = (1.0f - z) * na + z * hp;
            h_out[(size_t)m * 512 + n] = ho;
            h_out_bf[(size_t)m * 512 + n] = f2bf(ho);
        }
    }
}

// ---------------------------------------------------------------------------
// Fused u + attention + out_proj. One block per batch row b; 1024 threads
// (16 waves). u and fc are per-row GEMVs from LDS (wU/wFc are L2-resident).
__global__ __launch_bounds__(1024) void attn_fused(const float* __restrict__ h1,
                                                   const ush* __restrict__ wU,
                                                   const float* __restrict__ Ub,
                                                   const float* __restrict__ vw,
                                                   const ush* __restrict__ Ws_bf,
                                                   const ush* __restrict__ enc_bf,
                                                   const ush* __restrict__ wFc,
                                                   const float* __restrict__ fcb,
                                                   ush* __restrict__ y_bf,
                                                   ush* __restrict__ ys_bf) {
    int b = blockIdx.x;
    int tid = threadIdx.x;
    int lane = tid & 63, wave = tid >> 6;
    __shared__ float hs[512];
    __shared__ float urow[512];
    __shared__ float ctxrow[512];
    __shared__ float sc[SS];
    __shared__ float psum[1024];
    // stage h1 row (fp32)
    if (tid < 256) {
        float2 hv = ((const float2*)(h1 + (size_t)b * 512))[tid];
        hs[tid * 2] = hv.x;
        hs[tid * 2 + 1] = hv.y;
    }
    __syncthreads();
    // ---- u GEMV: n = tid>>1, k-half = tid&1 (256 MACs each)
    {
        int n = tid >> 1, half = tid & 1;
        const ush* w = wU + (size_t)n * 512 + half * 256;
        const float* hh = hs + half * 256;
        float s = 0.f;
#pragma unroll 4
        for (int k = 0; k < 256; k += 8) {
            short8 wv = *(const short8*)(w + k);
#pragma unroll
            for (int j = 0; j < 8; j++) s += hh[k + j] * bf2f((ush)wv[j]);
        }
        psum[tid] = s;
    }
    __syncthreads();
    if (tid < 512) urow[tid] = psum[tid * 2] + psum[tid * 2 + 1] + Ub[tid];
    __syncthreads();
    // ---- scores: 16 waves x 8 s-rows
    {
        int col = lane * 8;
        float ur[8], vr[8];
#pragma unroll
        for (int qq = 0; qq < 8; qq++) ur[qq] = urow[col + qq];
        float4 v0 = *(const float4*)(vw + col);
        float4 v1 = *(const float4*)(vw + col + 4);
        vr[0] = v0.x; vr[1] = v0.y; vr[2] = v0.z; vr[3] = v0.w;
        vr[4] = v1.x; vr[5] = v1.y; vr[6] = v1.z; vr[7] = v1.w;
        const ush* wsb = Ws_bf + (size_t)b * SS * HH;
        int s0 = wave * 8;
        float p[8];
#pragma unroll
        for (int j = 0; j < 8; j++) {
            short8 rv = *(const short8*)(wsb + (size_t)(s0 + j) * HH + col);
            float acc = 0.0f;
#pragma unroll
            for (int qq = 0; qq < 8; qq++) {
                float e = bf2f((ush)rv[qq]) + ur[qq];
                acc += fmaxf(e, 0.0f) * vr[qq];
            }
            p[j] = acc;
        }
#pragma unroll
        for (int off = 32; off > 0; off >>= 1)
#pragma unroll
            for (int j = 0; j < 8; j++) p[j] += __shfl_xor(p[j], off);
        float out = p[0];
#pragma unroll
        for (int j = 1; j < 8; j++)
            if (lane == j) out = p[j];
        if (lane < 8) sc[s0 + lane] = out;
    }
    __syncthreads();
    if (wave == 0) {
        float s0v = sc[lane], s1v = sc[lane + 64];
        float m = wave_max(fmaxf(s0v, s1v));
        float e0 = expf(s0v - m), e1 = expf(s1v - m);
        float ssum = wave_sum(e0 + e1);
        float inv = 1.0f / ssum;
        sc[lane] = e0 * inv;
        sc[lane + 64] = e1 * inv;
    }
    __syncthreads();
    // ---- ctx: 16 waves x 32 c (4 groups of 8 chains)
    {
        float ax = sc[lane * 2], ay = sc[lane * 2 + 1];
        const ush* eb = enc_bf + (size_t)b * CC * SS;
#pragma unroll
        for (int g = 0; g < 4; g++) {
            float p[8];
#pragma unroll
            for (int j = 0; j < 8; j++) {
                int c = wave * 32 + g * 8 + j;
                unsigned ev = *(const unsigned*)(eb + (size_t)c * SS + lane * 2);
                float flo = __uint_as_float(ev << 16);
                float fhi = __uint_as_float(ev & 0xFFFF0000u);
                p[j] = flo * ax + fhi * ay;
            }
#pragma unroll
            for (int off = 32; off > 0; off >>= 1)
#pragma unroll
                for (int j = 0; j < 8; j++) p[j] += __shfl_xor(p[j], off);
            float out = p[0];
#pragma unroll
            for (int j = 1; j < 8; j++)
                if (lane == j) out = p[j];
            if (lane < 8) ctxrow[wave * 32 + g * 8 + lane] = out;
        }
    }
    __syncthreads();
    // ---- fc GEMV: n = tid>>1; half 0 -> ctx part, half 1 -> h1 part (512 MACs)
    {
        int n = tid >> 1, half = tid & 1;
        const ush* w = wFc + (size_t)n * 1024 + half * 512;
        const float* A = half ? hs : ctxrow;
        float s = 0.f;
#pragma unroll 4
        for (int k = 0; k < 512; k += 8) {
            short8 wv = *(const short8*)(w + k);
#pragma unroll
            for (int j = 0; j < 8; j++) s += A[k + j] * bf2f((ush)wv[j]);
        }
        psum[tid] = s;
    }
    __syncthreads();
    if (tid < 512) {
        float v = fmaxf(psum[tid * 2] + psum[tid * 2 + 1] + fcb[tid], 0.0f);
        ush bv = f2bf(v);
        y_bf[(size_t)b * 512 + tid] = bv;
        if (ys_bf) ys_bf[(size_t)b * 512 + tid] = bv;
    }
}

// ---------------------------------------------------------------------------
// cls GEMM: M=5888, N=64, K=512. 92 blocks.
__global__ __launch_bounds__(256) void cls_kernel(const ush* __restrict__ ys_bf,
                                                  const ush* __restrict__ wCls,
                                                  float* __restrict__ logits) {
    int i = blockIdx.x;
    int tid = threadIdx.x;
    int wave = tid >> 6, lane = tid & 63;
    int quad = lane >> 4, l16 = lane & 15;
    int m0 = i * 64 + wave * 16;
    const ush* xp = ys_bf + (size_t)(m0 + l16) * 512 + quad * 8;
    const ush* wp = wCls + (size_t)l16 * 512 + quad * 8;
    f32x4 acc4[4];
#pragma unroll
    for (int s = 0; s < 4; s++) acc4[s] = (f32x4){0.f, 0.f, 0.f, 0.f};
    mfma_tile64(xp, wp, 512, acc4);
    float* Lb = logits + (size_t)(m0 + quad * 4) * 64 + l16;
#pragma unroll
    for (int s = 0; s < 4; s++)
#pragma unroll
        for (int rr = 0; rr < 4; rr++) Lb[(size_t)rr * 64 + s * 16] = acc4[s][rr];
}

// NLL over logits + cls bias. grid 256, block 256 (4 waves).
__global__ __launch_bounds__(256) void nll_kernel(const float* __restrict__ logits,
                                                  const float* __restrict__ cls_b,
                                                  const int* __restrict__ seq,
                                                  float* __restrict__ acc) {
    int tid = threadIdx.x;
    int wave = tid >> 6, lane = tid & 63;
    float biasv = cls_b[lane];
    float lsum = 0.0f, lcnt = 0.0f;
    for (int item = blockIdx.x * 4 + wave; item < 5888; item += gridDim.x * 4) {
        int t = item >> 8, b = item & 255;
        float v = logits[(size_t)item * 64 + lane] + biasv;
        float m = wave_max(v);
        float e = expf(v - m);
        float s = wave_sum(e);
        int label = seq[b * LL + t + 1];
        float vl = __shfl(v, label);
        if (lane == 0 && label > 0) {
            lsum += -(vl - m - logf(s));
            lcnt += 1.0f;
        }
    }
    if (lane == 0 && (lsum != 0.0f || lcnt != 0.0f)) {
        atomicAdd(&acc[0], lsum);
        atomicAdd(&acc[1], lcnt);
    }
}

__global__ void final_kernel(const float* __restrict__ acc, float* __restrict__ out) {
    if (threadIdx.x == 0) out[0] = acc[0] / acc[1];
}

// ---------------------------------------------------------------------------
extern "C" void kernel_launch(void* const* d_in, const int* in_sizes, int n_in,
                              void* d_out, int out_size, void* d_ws, size_t ws_size,
                              hipStream_t stream) {
    const float* enc        = (const float*)d_in[0];
    const int*   seq        = (const int*)d_in[1];
    const float* embed_w    = (const float*)d_in[3];
    const float* init_state = (const float*)d_in[4];
    const float* attn_W_w   = (const float*)d_in[5];
    const float* attn_W_b   = (const float*)d_in[6];
    const float* attn_U_w   = (const float*)d_in[7];
    const float* attn_U_b   = (const float*)d_in[8];
    const float* attn_v_w   = (const float*)d_in[9];
    const float* fc_w       = (const float*)d_in[11];
    const float* fc_b       = (const float*)d_in[12];
    const float* cls_w      = (const float*)d_in[13];
    const float* cls_b      = (const float*)d_in[14];
    const float* g0_wih     = (const float*)d_in[15];
    const float* g0_whh     = (const float*)d_in[16];
    const float* g0_bih     = (const float*)d_in[17];
    const float* g0_bhh     = (const float*)d_in[18];
    const float* g1_wih     = (const float*)d_in[19];
    const float* g1_whh     = (const float*)d_in[20];
    const float* g1_bih     = (const float*)d_in[21];
    const float* g1_bhh     = (const float*)d_in[22];
    float* out = (float*)d_out;

    float* ws = (float*)d_ws;
    size_t o = 0;
    ush* Ws_bf   = (ush*)(ws + o); o += (size_t)BB * SS * HH / 2;
    ush* enc_bf  = (ush*)(ws + o); o += (size_t)BB * CC * SS / 2;
    ush* ys_bf   = (ush*)(ws + o); o += (size_t)(LL - 1) * BB * HH / 2;
    ush* xall_bf = (ush*)(ws + o); o += (size_t)(LL - 1) * BB * HH / 2;
    ush* wWb  = (ush*)(ws + o); o += 262144 / 2;
    ush* wU   = (ush*)(ws + o); o += 262144 / 2;
    ush* wFc  = (ush*)(ws + o); o += 524288 / 2;
    ush* wCls = (ush*)(ws + o); o += 32768 / 2;
    ush* wG0i = (ush*)(ws + o); o += 1572864 / 2;
    ush* wG0h = (ush*)(ws + o); o += 786432 / 2;
    ush* wG1i = (ush*)(ws + o); o += 786432 / 2;
    ush* wG1h = (ush*)(ws + o); o += 786432 / 2;
    float* logits = ws + o; o += (size_t)(LL - 1) * BB * VV;
    float* h0a    = ws + o; o += (size_t)BB * HH;
    float* h0b    = ws + o; o += (size_t)BB * HH;
    float* h1a    = ws + o; o += (size_t)BB * HH;
    float* h1b    = ws + o; o += (size_t)BB * HH;
    float* accb   = ws + o; o += 256;
    ush* h0a_bf = (ush*)(ws + o); o += (size_t)BB * HH / 2;
    ush* h0b_bf = (ush*)(ws + o); o += (size_t)BB * HH / 2;
    ush* h1a_bf = (ush*)(ws + o); o += (size_t)BB * HH / 2;
    ush* h1b_bf = (ush*)(ws + o); o += (size_t)BB * HH / 2;
    ush* y_bf   = (ush*)(ws + o); o += (size_t)BB * HH / 2;

    // ---- prologue
    ConvAllArgs ca;
    ca.src[0] = attn_W_w; ca.dst[0] = wWb;
    ca.src[1] = attn_U_w; ca.dst[1] = wU;
    ca.src[2] = fc_w;     ca.dst[2] = wFc;
    ca.src[3] = cls_w;    ca.dst[3] = wCls;
    ca.src[4] = g0_wih;   ca.dst[4] = wG0i;
    ca.src[5] = g0_whh;   ca.dst[5] = wG0h;
    ca.src[6] = g1_wih;   ca.dst[6] = wG1i;
    ca.src[7] = g1_whh;   ca.dst[7] = wG1h;
    conv_all<<<4896, 256, 0, stream>>>(ca);
    conv_kernel<<<16384, 256, 0, stream>>>(enc, enc_bf, 4194304);
    gather_kernel<<<(LL - 1) * BB, 128, 0, stream>>>(embed_w, seq, xall_bf);
    ws_mfma<<<dim3(128, 8), 256, 0, stream>>>(enc, wWb, attn_W_b, Ws_bf);
    init_kernel<<<512, 256, 0, stream>>>(init_state, h0a, h1a, h0a_bf, h1a_bf, accb);

    // y0 = out_proj(attn(h1_0), h1_0)
    attn_fused<<<BB, 1024, 0, stream>>>(h1a, wU, attn_U_b, attn_v_w, Ws_bf, enc_bf,
                                        wFc, fc_b, y_bf, nullptr);

    float* h0_in = h0a; float* h0_out = h0b;
    float* h1_in = h1a; float* h1_out = h1b;
    ush* h0_in_bf = h0a_bf; ush* h0_out_bf = h0b_bf;
    ush* h1_in_bf = h1a_bf; ush* h1_out_bf = h1b_bf;
    for (int t = 0; t < LL - 1; t++) {
        gru3<true, 1024><<<512, 192, 0, stream>>>(
            y_bf, xall_bf + (size_t)t * BB * HH, h0_in_bf,
            wG0i, wG0h, g0_bih, g0_bhh, h0_in, h0_out, h0_out_bf);
        gru3<false, 512><<<512, 192, 0, stream>>>(
            h0_out_bf, nullptr, h1_in_bf,
            wG1i, wG1h, g1_bih, g1_bhh, h1_in, h1_out, h1_out_bf);
        attn_fused<<<BB, 1024, 0, stream>>>(h1_out, wU, attn_U_b, attn_v_w, Ws_bf,
                                            enc_bf, wFc, fc_b, y_bf,
                                            ys_bf + (size_t)t * BB * HH);
        float* tf;
        tf = h0_in; h0_in = h0_out; h0_out = tf;
        tf = h1_in; h1_in = h1_out; h1_out = tf;
        ush* tb;
        tb = h0_in_bf; h0_in_bf = h0_out_bf; h0_out_bf = tb;
        tb = h1_in_bf; h1_in_bf = h1_out_bf; h1_out_bf = tb;
    }

    cls_kernel<<<92, 256, 0, stream>>>(ys_bf, wCls, logits);
    nll_kernel<<<256, 256, 0, stream>>>(logits, cls_b, seq, accb);
    final_kernel<<<1, 64, 0, stream>>>(accb, out);
}